// Round 1
// baseline (237.092 us; speedup 1.0000x reference)
//
#include <hip/hip_runtime.h>
#include <hip/hip_bf16.h>

#define NB 128        // batch B
#define NMEM 100000   // N
#define ND 128        // D
constexpr float T_INV = 1.0f / 0.07f;

constexpr int LROW = ND + 8;   // 136 bf16 per LDS row = 272 B (16B-aligned rows, breaks pow2 stride)
constexpr int TILE = 128;      // feats rows per workgroup
constexpr int NTILES = (NMEM + TILE - 1) / TILE;  // 782
constexpr int ZSTRIDE = 16;    // Z slots 64B apart -> atomic chains on distinct cache lines

typedef __attribute__((ext_vector_type(8))) __bf16 bf16x8;
typedef __attribute__((ext_vector_type(4))) float f32x4;

// D = A*B: A-frag lane layout A[m=lane&15][k=(lane>>4)*8+j], B-frag B[n=lane&15][k=(lane>>4)*8+j]
// C/D: col(n)=lane&15, row(m)=(lane>>4)*4+reg   [HW-verified m89/m91]
template<bool PASS2>
__global__ __launch_bounds__(256, 2) void nce_pass(
    const float* __restrict__ x,
    const int* __restrict__ labels,
    const float* __restrict__ mem_da,
    float* __restrict__ zbuf,
    float* __restrict__ out,
    float* __restrict__ maskout)
{
  __shared__ __bf16 xs[NB * LROW];     // 34816 B
  __shared__ __bf16 fs[TILE * LROW];   // 34816 B
  __shared__ float lbl_n[TILE];
  __shared__ float lbl_b[NB];
  __shared__ float rz[NB];
  __shared__ float zl[NB];

  const int tid = threadIdx.x;
  const int t = blockIdx.x;

  // ---- stage x: 16384 f32 -> bf16 LDS, coalesced float4 ----
  const float4* x4 = (const float4*)x;
  #pragma unroll
  for (int i = 0; i < 16; ++i) {
    int g4 = tid + i * 256;          // 0..4095
    float4 v = x4[g4];
    int row = g4 >> 5;               // 32 float4 per row
    int col = (g4 & 31) * 4;
    __bf16* p = &xs[row * LROW + col];
    p[0] = (__bf16)v.x; p[1] = (__bf16)v.y; p[2] = (__bf16)v.z; p[3] = (__bf16)v.w;
  }

  // ---- stage feats tile: contiguous span over stride-129 rows, de-interleave ----
  const int rows = min(TILE, NMEM - t * TILE);   // 128, last block 32
  const int count4 = rows * 129 / 4;             // rows%4==0 -> exact
  const float4* f4 = (const float4*)(mem_da + (size_t)t * (TILE * 129));
  for (int i = tid; i < count4; i += 256) {
    float4 v = f4[i];
    unsigned g = 4u * (unsigned)i;
    #pragma unroll
    for (int c = 0; c < 4; ++c) {
      float val = (&v.x)[c];
      unsigned gg = g + c;
      unsigned r = gg / 129u;        // compiler magic-div
      unsigned cc = gg - r * 129u;
      if (cc == 0) lbl_n[r] = val;   // bank label column
      else fs[r * LROW + (cc - 1)] = (__bf16)val;
    }
  }

  if (PASS2) {
    if (tid < NB) {
      lbl_b[tid] = (float)labels[tid];
      rz[tid] = 1.0f / zbuf[tid * ZSTRIDE];
    }
  } else {
    if (tid < NB) zl[tid] = 0.0f;
  }
  __syncthreads();

  const int wid = tid >> 6;
  const int lane = tid & 63;
  const int q = lane >> 4;
  const int l16 = lane & 15;
  const int nbase = t * TILE + wid * 32;   // this wave's 32 n-columns

  if (nbase < NMEM) {                      // 100000 % 32 == 0: wave tiles are never ragged
    f32x4 acc[8][2];
    #pragma unroll
    for (int mt = 0; mt < 8; ++mt) {
      acc[mt][0] = (f32x4){0.f, 0.f, 0.f, 0.f};
      acc[mt][1] = (f32x4){0.f, 0.f, 0.f, 0.f};
    }

    #pragma unroll
    for (int kc = 0; kc < 4; ++kc) {
      const int ko = kc * 32 + q * 8;
      bf16x8 b0 = *(const bf16x8*)&fs[(wid * 32 + l16) * LROW + ko];
      bf16x8 b1 = *(const bf16x8*)&fs[(wid * 32 + 16 + l16) * LROW + ko];
      #pragma unroll
      for (int mt = 0; mt < 8; ++mt) {
        bf16x8 a = *(const bf16x8*)&xs[(mt * 16 + l16) * LROW + ko];
        acc[mt][0] = __builtin_amdgcn_mfma_f32_16x16x32_bf16(a, b0, acc[mt][0], 0, 0, 0);
        acc[mt][1] = __builtin_amdgcn_mfma_f32_16x16x32_bf16(a, b1, acc[mt][1], 0, 0, 0);
      }
    }

    if (!PASS2) {
      // Z partial: exp, then sum over this wave's 32 n (2 in-reg + 16-lane butterfly)
      #pragma unroll
      for (int mt = 0; mt < 8; ++mt) {
        #pragma unroll
        for (int r = 0; r < 4; ++r) {
          float v = __expf(acc[mt][0][r] * T_INV) + __expf(acc[mt][1][r] * T_INV);
          v += __shfl_xor(v, 1);
          v += __shfl_xor(v, 2);
          v += __shfl_xor(v, 4);
          v += __shfl_xor(v, 8);
          if (l16 == 0) atomicAdd(&zl[mt * 16 + q * 4 + r], v);  // m = mt*16+q*4+r
        }
      }
    } else {
      float ln0 = lbl_n[wid * 32 + l16];
      float ln1 = lbl_n[wid * 32 + 16 + l16];
      #pragma unroll
      for (int mt = 0; mt < 8; ++mt) {
        #pragma unroll
        for (int r = 0; r < 4; ++r) {
          int m = mt * 16 + q * 4 + r;
          float rzm = rz[m];
          float lb = lbl_b[m];
          size_t base = (size_t)m * NMEM + nbase + l16;
          out[base]      = __expf(acc[mt][0][r] * T_INV) * rzm;
          out[base + 16] = __expf(acc[mt][1][r] * T_INV) * rzm;
          maskout[base]      = (ln0 == lb) ? 1.0f : 0.0f;
          maskout[base + 16] = (ln1 == lb) ? 1.0f : 0.0f;
        }
      }
    }
  }

  if (!PASS2) {
    __syncthreads();
    if (tid < NB) atomicAdd(&zbuf[tid * ZSTRIDE], zl[tid]);
  }
}

extern "C" void kernel_launch(void* const* d_in, const int* in_sizes, int n_in,
                              void* d_out, int out_size, void* d_ws, size_t ws_size,
                              hipStream_t stream) {
  const float* x      = (const float*)d_in[0];
  const int* labels   = (const int*)d_in[2];
  const float* mem_da = (const float*)d_in[3];
  float* out     = (float*)d_out;
  float* maskout = out + (size_t)NB * NMEM;
  float* zbuf    = (float*)d_ws;   // 128 * 16 floats = 8 KB

  hipMemsetAsync(zbuf, 0, NB * ZSTRIDE * sizeof(float), stream);
  nce_pass<false><<<NTILES, 256, 0, stream>>>(x, labels, mem_da, zbuf, nullptr, nullptr);
  nce_pass<true ><<<NTILES, 256, 0, stream>>>(x, labels, mem_da, zbuf, out, maskout);
}

// Round 2
// 224.904 us; speedup vs baseline: 1.0542x; 1.0542x over previous
//
#include <hip/hip_runtime.h>
#include <hip/hip_bf16.h>

#define NB 128        // batch B
#define NMEM 100000   // N
#define ND 128        // D
constexpr float T_INV = 1.0f / 0.07f;

constexpr int LROW = ND + 8;   // 136 bf16 per LDS row = 272 B
constexpr int TILE = 128;      // feats rows per workgroup
constexpr int NTILES = (NMEM + TILE - 1) / TILE;  // 782
constexpr int ZSTRIDE = 16;    // Z slots 64B apart
constexpr int C4FULL = TILE * 129 / 4;            // 4128 float4 per full tile
constexpr int NITER = (C4FULL + 255) / 256;       // 17

typedef __attribute__((ext_vector_type(8))) __bf16 bf16x8;
typedef __attribute__((ext_vector_type(4))) float f32x4;
struct bf4 { __bf16 a, b, c, d; };   // 8-byte LDS store unit

// A-frag: A[m=lane&15][k=(lane>>4)*8+j]; B-frag: B[n=lane&15][k=(lane>>4)*8+j]
// C/D: col(n)=lane&15, row(m)=(lane>>4)*4+reg   [HW-verified m89/m91]
template<bool PASS2>
__global__ __launch_bounds__(256, 2) void nce_pass(
    const float* __restrict__ x,
    const int* __restrict__ labels,
    const float* __restrict__ mem_da,
    float* __restrict__ zbuf,
    float* __restrict__ out,
    float* __restrict__ maskout)
{
  __shared__ __bf16 xs[NB * LROW];     // 34816 B
  __shared__ __bf16 fs[TILE * LROW];   // 34816 B
  __shared__ float lbl_n[TILE];
  __shared__ float lbl_b[NB];
  __shared__ float rz[NB];
  __shared__ float zl[NB];

  const int tid = threadIdx.x;
  const int t = blockIdx.x;
  const int count4 = (t == NTILES - 1) ? (NMEM - t * TILE) * 129 / 4 : C4FULL;

  // ---- batched loads: issue ALL staging loads before any wait ----
  const float4* f4 = (const float4*)(mem_da + (size_t)t * (TILE * 129));
  float4 fv[NITER];
  #pragma unroll
  for (int i = 0; i < NITER; ++i) {
    int idx = tid + i * 256;
    fv[i] = f4[idx < count4 ? idx : 0];
  }
  const float4* x4 = (const float4*)x;
  float4 xv[16];
  #pragma unroll
  for (int i = 0; i < 16; ++i) xv[i] = x4[tid + i * 256];

  // ---- x -> bf16 LDS (8B stores) ----
  #pragma unroll
  for (int i = 0; i < 16; ++i) {
    int g4 = tid + i * 256;
    int row = g4 >> 5;
    int col = (g4 & 31) * 4;
    *(bf4*)&xs[row * LROW + col] =
        bf4{(__bf16)xv[i].x, (__bf16)xv[i].y, (__bf16)xv[i].z, (__bf16)xv[i].w};
  }

  // ---- feats de-interleave (1 div per float4) ----
  #pragma unroll
  for (int i = 0; i < NITER; ++i) {
    int idx = tid + i * 256;
    if (idx < count4) {
      unsigned g = 4u * (unsigned)idx;
      unsigned r = g / 129u;
      unsigned cc = g - r * 129u;
      float4 v = fv[i];
      #pragma unroll
      for (int c = 0; c < 4; ++c) {
        float val = (&v.x)[c];
        if (cc == 0) lbl_n[r] = val;
        else fs[r * LROW + (cc - 1)] = (__bf16)val;
        if (++cc == 129u) { cc = 0; ++r; }
      }
    }
  }

  if (tid < NB) {
    lbl_b[tid] = (float)labels[tid];
    if (PASS2) rz[tid] = 1.0f / zbuf[tid * ZSTRIDE];
    else zl[tid] = 0.0f;
  }
  __syncthreads();

  const int wid = tid >> 6;
  const int lane = tid & 63;
  const int q = lane >> 4;
  const int l16 = lane & 15;
  const int nbase = t * TILE + wid * 32;

  if (nbase < NMEM) {                  // 100000 % 32 == 0: wave tiles never ragged
    f32x4 acc[8][2];
    #pragma unroll
    for (int mt = 0; mt < 8; ++mt) {
      acc[mt][0] = (f32x4){0.f, 0.f, 0.f, 0.f};
      acc[mt][1] = (f32x4){0.f, 0.f, 0.f, 0.f};
    }
    #pragma unroll
    for (int kc = 0; kc < 4; ++kc) {
      const int ko = kc * 32 + q * 8;
      bf16x8 b0 = *(const bf16x8*)&fs[(wid * 32 + l16) * LROW + ko];
      bf16x8 b1 = *(const bf16x8*)&fs[(wid * 32 + 16 + l16) * LROW + ko];
      #pragma unroll
      for (int mt = 0; mt < 8; ++mt) {
        bf16x8 a = *(const bf16x8*)&xs[(mt * 16 + l16) * LROW + ko];
        acc[mt][0] = __builtin_amdgcn_mfma_f32_16x16x32_bf16(a, b0, acc[mt][0], 0, 0, 0);
        acc[mt][1] = __builtin_amdgcn_mfma_f32_16x16x32_bf16(a, b1, acc[mt][1], 0, 0, 0);
      }
    }

    if (!PASS2) {
      // mask writes + Z partials
      float ln0 = lbl_n[wid * 32 + l16];
      float ln1 = lbl_n[wid * 32 + 16 + l16];
      #pragma unroll
      for (int mt = 0; mt < 8; ++mt) {
        #pragma unroll
        for (int r = 0; r < 4; ++r) {
          int m = mt * 16 + q * 4 + r;
          float lb = lbl_b[m];
          size_t base = (size_t)m * NMEM + nbase + l16;
          maskout[base]      = (ln0 == lb) ? 1.0f : 0.0f;
          maskout[base + 16] = (ln1 == lb) ? 1.0f : 0.0f;
          float v = __expf(acc[mt][0][r] * T_INV) + __expf(acc[mt][1][r] * T_INV);
          v += __shfl_xor(v, 1);
          v += __shfl_xor(v, 2);
          v += __shfl_xor(v, 4);
          v += __shfl_xor(v, 8);
          if (l16 == 0) atomicAdd(&zl[m], v);
        }
      }
    } else {
      #pragma unroll
      for (int mt = 0; mt < 8; ++mt) {
        #pragma unroll
        for (int r = 0; r < 4; ++r) {
          int m = mt * 16 + q * 4 + r;
          float rzm = rz[m];
          size_t base = (size_t)m * NMEM + nbase + l16;
          out[base]      = __expf(acc[mt][0][r] * T_INV) * rzm;
          out[base + 16] = __expf(acc[mt][1][r] * T_INV) * rzm;
        }
      }
    }
  }

  if (!PASS2) {
    __syncthreads();
    if (tid < NB) atomicAdd(&zbuf[tid * ZSTRIDE], zl[tid]);
  }
}

extern "C" void kernel_launch(void* const* d_in, const int* in_sizes, int n_in,
                              void* d_out, int out_size, void* d_ws, size_t ws_size,
                              hipStream_t stream) {
  const float* x      = (const float*)d_in[0];
  const int* labels   = (const int*)d_in[2];
  const float* mem_da = (const float*)d_in[3];
  float* out     = (float*)d_out;
  float* maskout = out + (size_t)NB * NMEM;
  float* zbuf    = (float*)d_ws;

  hipMemsetAsync(zbuf, 0, NB * ZSTRIDE * sizeof(float), stream);
  nce_pass<false><<<NTILES, 256, 0, stream>>>(x, labels, mem_da, zbuf, nullptr, maskout);
  nce_pass<true ><<<NTILES, 256, 0, stream>>>(x, labels, mem_da, zbuf, out, nullptr);
}